// Round 3
// baseline (253.739 us; speedup 1.0000x reference)
//
#include <hip/hip_runtime.h>

#define HW      147456           // 384*384
#define NC      5
#define NT      40               // 4*10
#define NPIX    (NT * HW)        // 5,898,240
#define NGROUP  (NPIX / 4)       // 1,474,560 float4 groups
#define NBLOCKS 1440
#define SMOOTH  1e-5f

// Workspace layout (first 64 bytes, zeroed by hipMemsetAsync each launch):
//   ws[0..4]   sum(x) per class
//   ws[5..9]   sum(x * onehot) per class
//   ws[10..14] onehot count per class
//   ws[15]     ticket counter (as unsigned)
// Single dispatch: every block accumulates via device-scope atomics, the
// last block (ticket == NBLOCKS-1) computes and stores the scalar loss.

__global__ __launch_bounds__(256) void dice_fused(const float* __restrict__ inp,
                                                  const float* __restrict__ tgt,
                                                  const float* __restrict__ w,
                                                  float* __restrict__ ws,
                                                  float* __restrict__ out) {
    float sumx[NC]  = {0.f, 0.f, 0.f, 0.f, 0.f};
    float inter[NC] = {0.f, 0.f, 0.f, 0.f, 0.f};
    float cnt[NC]   = {0.f, 0.f, 0.f, 0.f, 0.f};

    const int tid    = blockIdx.x * 256 + threadIdx.x;
    const int stride = gridDim.x * 256;

    for (int g = tid; g < NGROUP; g += stride) {
        const int p  = g << 2;            // pixel index; also the flat target index
        const int nt = p / HW;            // magic-mul division by 147456
        const int hw = p - nt * HW;

        const float4 t4 = reinterpret_cast<const float4*>(tgt)[g];
        const int c0 = (t4.x >= 0.25f) + (t4.x >= 0.375f) + (t4.x >= 0.5f) + (t4.x >= 0.625f);
        const int c1 = (t4.y >= 0.25f) + (t4.y >= 0.375f) + (t4.y >= 0.5f) + (t4.y >= 0.625f);
        const int c2 = (t4.z >= 0.25f) + (t4.z >= 0.375f) + (t4.z >= 0.5f) + (t4.z >= 0.625f);
        const int c3 = (t4.w >= 0.25f) + (t4.w >= 0.375f) + (t4.w >= 0.5f) + (t4.w >= 0.625f);

        const float* base = inp + (size_t)nt * (size_t)(NC * HW) + (size_t)hw;
        #pragma unroll
        for (int c = 0; c < NC; ++c) {
            const float4 x4 = *reinterpret_cast<const float4*>(base + (size_t)c * HW);
            sumx[c] += (x4.x + x4.y) + (x4.z + x4.w);
            float iv = 0.f;
            if (c0 == c) iv += x4.x;
            if (c1 == c) iv += x4.y;
            if (c2 == c) iv += x4.z;
            if (c3 == c) iv += x4.w;
            inter[c] += iv;
            cnt[c]   += (float)((c0 == c) + (c1 == c) + (c2 == c) + (c3 == c));
        }
    }

    // pack 15 accumulators: [0..4]=sumx, [5..9]=inter, [10..14]=cnt
    float v[15];
    #pragma unroll
    for (int c = 0; c < NC; ++c) { v[c] = sumx[c]; v[5 + c] = inter[c]; v[10 + c] = cnt[c]; }

    // wave-64 butterfly reduce
    #pragma unroll
    for (int j = 0; j < 15; ++j) {
        #pragma unroll
        for (int off = 32; off > 0; off >>= 1)
            v[j] += __shfl_down(v[j], off, 64);
    }

    __shared__ float part[4][15];
    const int lane = threadIdx.x & 63;
    const int wv   = threadIdx.x >> 6;
    if (lane == 0) {
        #pragma unroll
        for (int j = 0; j < 15; ++j) part[wv][j] = v[j];
    }
    __syncthreads();
    if (threadIdx.x < 15) {
        const float s = part[0][threadIdx.x] + part[1][threadIdx.x] +
                        part[2][threadIdx.x] + part[3][threadIdx.x];
        atomicAdd(&ws[threadIdx.x], s);
    }

    // __syncthreads drains vmcnt -> all 15 atomics of this block have completed
    __syncthreads();

    if (threadIdx.x == 0) {
        __threadfence();                               // release
        const unsigned old = atomicAdd(reinterpret_cast<unsigned*>(ws + 15), 1u);
        if (old == NBLOCKS - 1) {                      // last block finishes
            __threadfence();                           // acquire
            float red[15];
            #pragma unroll
            for (int j = 0; j < 15; ++j)
                red[j] = __hip_atomic_load(ws + j, __ATOMIC_RELAXED,
                                           __HIP_MEMORY_SCOPE_AGENT);
            float loss = 0.f;
            #pragma unroll
            for (int c = 0; c < NC; ++c) {
                const float inter_c = red[5 + c];
                const float denom   = red[c] + red[10 + c];
                loss += w[c] * (1.f - (2.f * inter_c + SMOOTH) / (denom + SMOOTH));
            }
            out[0] = loss;
        }
    }
}

extern "C" void kernel_launch(void* const* d_in, const int* in_sizes, int n_in,
                              void* d_out, int out_size, void* d_ws, size_t ws_size,
                              hipStream_t stream) {
    const float* inp = (const float*)d_in[0];
    const float* tgt = (const float*)d_in[1];
    const float* wgt = (const float*)d_in[2];
    float* out = (float*)d_out;
    float* ws  = (float*)d_ws;

    hipMemsetAsync(ws, 0, 64, stream);   // zero 15 accumulators + ticket counter
    dice_fused<<<NBLOCKS, 256, 0, stream>>>(inp, tgt, wgt, ws, out);
}

// Round 4
// 197.141 us; speedup vs baseline: 1.2871x; 1.2871x over previous
//
#include <hip/hip_runtime.h>

#define HW      147456           // 384*384
#define NC      5
#define NT      40               // 4*10
#define NPIX    (NT * HW)        // 5,898,240
#define NGROUP  (NPIX / 4)       // 1,474,560 float4 groups
#define GPS     (HW / 4)         // 36,864 groups per time-slice
#define NBLOCKS 1440
#define NTHREADS (NBLOCKS * 256) // 368,640 -> exactly 4 groups per thread
#define ITERS   4
#define SMOOTH  1e-5f

// ws layout: ws[j*NBLOCKS + b], j in [0,15): 0..4 sum(x), 5..9 inter, 10..14 count.
// Plain stores (no atomics, no init kernel, no fences) -> kernel-boundary coherence.

__global__ __launch_bounds__(256, 4) void dice_main(const float* __restrict__ inp,
                                                    const float* __restrict__ tgt,
                                                    float* __restrict__ ws) {
    const int tid = blockIdx.x * 256 + threadIdx.x;

    // ---- issue ALL 24 loads before any use: 4 target + 20 input float4 ----
    float4 t4[ITERS];
    const float* base[ITERS];
    #pragma unroll
    for (int it = 0; it < ITERS; ++it) {
        const int g   = tid + it * NTHREADS;     // < NGROUP, compile-time exact
        const int nt  = g / GPS;                 // magic-mul
        const int hw4 = g - nt * GPS;
        t4[it]   = reinterpret_cast<const float4*>(tgt)[g];
        base[it] = inp + (size_t)nt * (size_t)(NC * HW) + ((size_t)hw4 << 2);
    }

    float4 x4[ITERS][NC];
    #pragma unroll
    for (int it = 0; it < ITERS; ++it) {
        #pragma unroll
        for (int c = 0; c < NC; ++c)
            x4[it][c] = *reinterpret_cast<const float4*>(base[it] + (size_t)c * HW);
    }

    // ---- consume ----
    float sumx[NC]  = {0.f, 0.f, 0.f, 0.f, 0.f};
    float inter[NC] = {0.f, 0.f, 0.f, 0.f, 0.f};
    float cnt[NC]   = {0.f, 0.f, 0.f, 0.f, 0.f};

    #pragma unroll
    for (int it = 0; it < ITERS; ++it) {
        const float4 t = t4[it];
        const int c0 = (t.x >= 0.25f) + (t.x >= 0.375f) + (t.x >= 0.5f) + (t.x >= 0.625f);
        const int c1 = (t.y >= 0.25f) + (t.y >= 0.375f) + (t.y >= 0.5f) + (t.y >= 0.625f);
        const int c2 = (t.z >= 0.25f) + (t.z >= 0.375f) + (t.z >= 0.5f) + (t.z >= 0.625f);
        const int c3 = (t.w >= 0.25f) + (t.w >= 0.375f) + (t.w >= 0.5f) + (t.w >= 0.625f);

        #pragma unroll
        for (int c = 0; c < NC; ++c) {
            const float4 x = x4[it][c];
            sumx[c] += (x.x + x.y) + (x.z + x.w);
            float iv = 0.f;
            if (c0 == c) iv += x.x;
            if (c1 == c) iv += x.y;
            if (c2 == c) iv += x.z;
            if (c3 == c) iv += x.w;
            inter[c] += iv;
            cnt[c]   += (float)((c0 == c) + (c1 == c) + (c2 == c) + (c3 == c));
        }
    }

    // pack 15 accumulators: [0..4]=sumx, [5..9]=inter, [10..14]=cnt
    float v[15];
    #pragma unroll
    for (int c = 0; c < NC; ++c) { v[c] = sumx[c]; v[5 + c] = inter[c]; v[10 + c] = cnt[c]; }

    // wave-64 butterfly reduce
    #pragma unroll
    for (int j = 0; j < 15; ++j) {
        #pragma unroll
        for (int off = 32; off > 0; off >>= 1)
            v[j] += __shfl_down(v[j], off, 64);
    }

    __shared__ float part[4][15];
    const int lane = threadIdx.x & 63;
    const int wv   = threadIdx.x >> 6;
    if (lane == 0) {
        #pragma unroll
        for (int j = 0; j < 15; ++j) part[wv][j] = v[j];
    }
    __syncthreads();
    if (threadIdx.x < 15) {
        const float s = part[0][threadIdx.x] + part[1][threadIdx.x] +
                        part[2][threadIdx.x] + part[3][threadIdx.x];
        ws[threadIdx.x * NBLOCKS + blockIdx.x] = s;   // plain store, coalesced read later
    }
}

__global__ __launch_bounds__(960) void dice_final(const float* __restrict__ ws,
                                                  const float* __restrict__ w,
                                                  float* __restrict__ out) {
    __shared__ float red[15];
    const int j    = threadIdx.x >> 6;   // 15 waves, one per accumulator slot
    const int lane = threadIdx.x & 63;

    float s = 0.f;
    for (int b = lane; b < NBLOCKS; b += 64)   // 22-23 coalesced iters, L2-resident
        s += ws[j * NBLOCKS + b];

    #pragma unroll
    for (int off = 32; off > 0; off >>= 1)
        s += __shfl_down(s, off, 64);

    if (lane == 0) red[j] = s;
    __syncthreads();

    if (threadIdx.x == 0) {
        float loss = 0.f;
        #pragma unroll
        for (int c = 0; c < NC; ++c) {
            const float inter = red[5 + c];
            const float denom = red[c] + red[10 + c];
            loss += w[c] * (1.f - (2.f * inter + SMOOTH) / (denom + SMOOTH));
        }
        out[0] = loss;
    }
}

extern "C" void kernel_launch(void* const* d_in, const int* in_sizes, int n_in,
                              void* d_out, int out_size, void* d_ws, size_t ws_size,
                              hipStream_t stream) {
    const float* inp = (const float*)d_in[0];
    const float* tgt = (const float*)d_in[1];
    const float* wgt = (const float*)d_in[2];
    float* out = (float*)d_out;
    float* ws  = (float*)d_ws;

    dice_main<<<NBLOCKS, 256, 0, stream>>>(inp, tgt, ws);
    dice_final<<<1, 960, 0, stream>>>(ws, wgt, out);
}

// Round 5
// 191.344 us; speedup vs baseline: 1.3261x; 1.0303x over previous
//
#include <hip/hip_runtime.h>

#define HW      147456           // 384*384 floats per (nt, c) slice
#define GPS     36864            // float4 groups per slice (HW/4)
#define NC      5
#define NT      40               // 4*10
#define BX      36               // 36 blocks * 1024 groups = 36864 = GPS
#define ITERS   4                // 256 thr * 4 = 1024 groups per block
#define NPB     1440             // NT*BX partials per (class, j) slot
#define SMOOTH  1e-5f

// Block (x, c, nt): streams input channel (nt,c) groups [x*1024, x*1024+1024)
// and the matching target groups. TWO contiguous streams per thread (copy-like),
// 3 scalar accumulators. Target is logically read 5x (once per class); the 4
// extra passes hit L3 (23.6 MB target << 256 MB L3).
// ws layout: ws[(c*3 + j)*NPB + (nt*BX + x)], j: 0=sumx 1=inter 2=cnt.

__global__ __launch_bounds__(256) void dice_main(const float* __restrict__ inp,
                                                 const float* __restrict__ tgt,
                                                 float* __restrict__ ws) {
    const int c  = blockIdx.y;               // class channel, wave-uniform
    const int nt = blockIdx.z;               // time-batch slice, wave-uniform
    const int g0 = blockIdx.x * 1024 + threadIdx.x;

    const float4* __restrict__ tb =
        reinterpret_cast<const float4*>(tgt + (size_t)nt * (size_t)HW);
    const float4* __restrict__ ib =
        reinterpret_cast<const float4*>(inp + ((size_t)nt * NC + c) * (size_t)HW);

    // issue all 8 loads (2 streams x 4) before consuming
    float4 t4[ITERS], x4[ITERS];
    #pragma unroll
    for (int it = 0; it < ITERS; ++it) {
        const int g = g0 + it * 256;         // contiguous 4 KB chunks per wave set
        t4[it] = tb[g];
        x4[it] = ib[g];
    }

    float sumx = 0.f, inter = 0.f, cntf = 0.f;
    #pragma unroll
    for (int it = 0; it < ITERS; ++it) {
        const float4 t = t4[it];
        const float4 x = x4[it];
        sumx += (x.x + x.y) + (x.z + x.w);

        const int b0 = (t.x >= 0.25f) + (t.x >= 0.375f) + (t.x >= 0.5f) + (t.x >= 0.625f);
        const int b1 = (t.y >= 0.25f) + (t.y >= 0.375f) + (t.y >= 0.5f) + (t.y >= 0.625f);
        const int b2 = (t.z >= 0.25f) + (t.z >= 0.375f) + (t.z >= 0.5f) + (t.z >= 0.625f);
        const int b3 = (t.w >= 0.25f) + (t.w >= 0.375f) + (t.w >= 0.5f) + (t.w >= 0.625f);

        float iv = 0.f, cv = 0.f;
        if (b0 == c) { iv += x.x; cv += 1.f; }
        if (b1 == c) { iv += x.y; cv += 1.f; }
        if (b2 == c) { iv += x.z; cv += 1.f; }
        if (b3 == c) { iv += x.w; cv += 1.f; }
        inter += iv;
        cntf  += cv;
    }

    // wave-64 butterfly reduce of 3 scalars
    float v[3] = {sumx, inter, cntf};
    #pragma unroll
    for (int j = 0; j < 3; ++j) {
        #pragma unroll
        for (int off = 32; off > 0; off >>= 1)
            v[j] += __shfl_down(v[j], off, 64);
    }

    __shared__ float part[4][3];
    const int lane = threadIdx.x & 63;
    const int wv   = threadIdx.x >> 6;
    if (lane == 0) {
        #pragma unroll
        for (int j = 0; j < 3; ++j) part[wv][j] = v[j];
    }
    __syncthreads();
    if (threadIdx.x < 3) {
        const float s = part[0][threadIdx.x] + part[1][threadIdx.x] +
                        part[2][threadIdx.x] + part[3][threadIdx.x];
        ws[((size_t)c * 3 + threadIdx.x) * NPB + (nt * BX + blockIdx.x)] = s;
    }
}

__global__ __launch_bounds__(960) void dice_final(const float* __restrict__ ws,
                                                  const float* __restrict__ w,
                                                  float* __restrict__ out) {
    __shared__ float red[15];
    const int s    = threadIdx.x >> 6;   // slot 0..14 = c*3 + j
    const int lane = threadIdx.x & 63;

    float acc = 0.f;
    for (int b = lane; b < NPB; b += 64)   // 23 coalesced iterations
        acc += ws[s * NPB + b];

    #pragma unroll
    for (int off = 32; off > 0; off >>= 1)
        acc += __shfl_down(acc, off, 64);

    if (lane == 0) red[s] = acc;
    __syncthreads();

    if (threadIdx.x == 0) {
        float loss = 0.f;
        #pragma unroll
        for (int c = 0; c < NC; ++c) {
            const float sumx  = red[c * 3 + 0];
            const float inter = red[c * 3 + 1];
            const float cnt   = red[c * 3 + 2];
            const float denom = sumx + cnt;
            loss += w[c] * (1.f - (2.f * inter + SMOOTH) / (denom + SMOOTH));
        }
        out[0] = loss;
    }
}

extern "C" void kernel_launch(void* const* d_in, const int* in_sizes, int n_in,
                              void* d_out, int out_size, void* d_ws, size_t ws_size,
                              hipStream_t stream) {
    const float* inp = (const float*)d_in[0];
    const float* tgt = (const float*)d_in[1];
    const float* wgt = (const float*)d_in[2];
    float* out = (float*)d_out;
    float* ws  = (float*)d_ws;

    dice_main<<<dim3(BX, NC, NT), 256, 0, stream>>>(inp, tgt, ws);
    dice_final<<<1, 960, 0, stream>>>(ws, wgt, out);
}

// Round 6
// 191.325 us; speedup vs baseline: 1.3262x; 1.0001x over previous
//
#include <hip/hip_runtime.h>

#define HW      147456           // 384*384 floats per (nt, c) slice
#define GPS     36864            // float4 groups per slice (HW/4)
#define NC      5
#define NT      40               // 4*10
#define BX      18               // chunks per slice: 18 * 2048 groups = 36864
#define NK      (BX * NT)        // 720 chunks total
#define ITERS   8                // 256 thr * 8 = 2048 groups (32 KB) per stream
#define NBLOCKS (NK * NC)        // 3600 blocks
#define SMOOTH  1e-5f

// Block decode (XCD-coherent mapping): flat f -> xcd = f%8, r = f/8,
// c = r%5, k = (r/5)*8 + xcd. All 5 class-blocks of chunk k share f%8 ->
// same XCD (round-robin dispatch) -> 4/5 target re-reads are local-L2 hits.
// Each block: ONE contiguous 32 KB input-channel run + matching 32 KB target
// run, 3 scalar accumulators (sumx, inter, cnt for class c).
// ws layout: ws[(c*3 + j)*NK + k], j: 0=sumx 1=inter 2=cnt.

__global__ __launch_bounds__(256) void dice_main(const float* __restrict__ inp,
                                                 const float* __restrict__ tgt,
                                                 float* __restrict__ ws) {
    const int f   = blockIdx.x;
    const int xcd = f & 7;
    const int r   = f >> 3;
    const int c   = r % 5;                    // class channel (wave-uniform)
    const int k   = (r / 5) * 8 + xcd;        // chunk id 0..719
    const int nt  = k / BX;                   // time-batch slice
    const int x   = k - nt * BX;              // chunk within slice

    const float4* __restrict__ tb =
        reinterpret_cast<const float4*>(tgt + (size_t)nt * (size_t)HW);
    const float4* __restrict__ ib =
        reinterpret_cast<const float4*>(inp + ((size_t)nt * NC + c) * (size_t)HW);

    const int g0 = x * (256 * ITERS) + threadIdx.x;

    // issue target loads first (mostly L2-hit for c>0), then input stream
    float4 t4[ITERS], x4[ITERS];
    #pragma unroll
    for (int it = 0; it < ITERS; ++it) t4[it] = tb[g0 + it * 256];
    #pragma unroll
    for (int it = 0; it < ITERS; ++it) x4[it] = ib[g0 + it * 256];

    float sumx = 0.f, inter = 0.f, cntf = 0.f;
    #pragma unroll
    for (int it = 0; it < ITERS; ++it) {
        const float4 t = t4[it];
        const float4 x4v = x4[it];
        sumx += (x4v.x + x4v.y) + (x4v.z + x4v.w);

        const int b0 = (t.x >= 0.25f) + (t.x >= 0.375f) + (t.x >= 0.5f) + (t.x >= 0.625f);
        const int b1 = (t.y >= 0.25f) + (t.y >= 0.375f) + (t.y >= 0.5f) + (t.y >= 0.625f);
        const int b2 = (t.z >= 0.25f) + (t.z >= 0.375f) + (t.z >= 0.5f) + (t.z >= 0.625f);
        const int b3 = (t.w >= 0.25f) + (t.w >= 0.375f) + (t.w >= 0.5f) + (t.w >= 0.625f);

        float iv = 0.f, cv = 0.f;
        if (b0 == c) { iv += x4v.x; cv += 1.f; }
        if (b1 == c) { iv += x4v.y; cv += 1.f; }
        if (b2 == c) { iv += x4v.z; cv += 1.f; }
        if (b3 == c) { iv += x4v.w; cv += 1.f; }
        inter += iv;
        cntf  += cv;
    }

    // wave-64 butterfly reduce of 3 scalars
    float v[3] = {sumx, inter, cntf};
    #pragma unroll
    for (int j = 0; j < 3; ++j) {
        #pragma unroll
        for (int off = 32; off > 0; off >>= 1)
            v[j] += __shfl_down(v[j], off, 64);
    }

    __shared__ float part[4][3];
    const int lane = threadIdx.x & 63;
    const int wv   = threadIdx.x >> 6;
    if (lane == 0) {
        #pragma unroll
        for (int j = 0; j < 3; ++j) part[wv][j] = v[j];
    }
    __syncthreads();
    if (threadIdx.x < 3) {
        const float s = part[0][threadIdx.x] + part[1][threadIdx.x] +
                        part[2][threadIdx.x] + part[3][threadIdx.x];
        ws[((size_t)c * 3 + threadIdx.x) * NK + k] = s;
    }
}

__global__ __launch_bounds__(960) void dice_final(const float* __restrict__ ws,
                                                  const float* __restrict__ w,
                                                  float* __restrict__ out) {
    __shared__ float red[15];
    const int s    = threadIdx.x >> 6;   // slot 0..14 = c*3 + j
    const int lane = threadIdx.x & 63;

    float acc = 0.f;
    for (int b = lane; b < NK; b += 64)   // 12 coalesced iterations, L2-resident
        acc += ws[s * NK + b];

    #pragma unroll
    for (int off = 32; off > 0; off >>= 1)
        acc += __shfl_down(acc, off, 64);

    if (lane == 0) red[s] = acc;
    __syncthreads();

    if (threadIdx.x == 0) {
        float loss = 0.f;
        #pragma unroll
        for (int c = 0; c < NC; ++c) {
            const float sumx  = red[c * 3 + 0];
            const float inter = red[c * 3 + 1];
            const float cnt   = red[c * 3 + 2];
            const float denom = sumx + cnt;
            loss += w[c] * (1.f - (2.f * inter + SMOOTH) / (denom + SMOOTH));
        }
        out[0] = loss;
    }
}

extern "C" void kernel_launch(void* const* d_in, const int* in_sizes, int n_in,
                              void* d_out, int out_size, void* d_ws, size_t ws_size,
                              hipStream_t stream) {
    const float* inp = (const float*)d_in[0];
    const float* tgt = (const float*)d_in[1];
    const float* wgt = (const float*)d_in[2];
    float* out = (float*)d_out;
    float* ws  = (float*)d_ws;

    dice_main<<<NBLOCKS, 256, 0, stream>>>(inp, tgt, ws);
    dice_final<<<1, 960, 0, stream>>>(ws, wgt, out);
}